// Round 11
// baseline (704.529 us; speedup 1.0000x reference)
//
#include <hip/hip_runtime.h>

#define WAVE 64
#define LRELU(x) ((x) > 0.0f ? (x) : 0.2f * (x))
#define SB0 __builtin_amdgcn_sched_barrier(0)

typedef __attribute__((ext_vector_type(8))) short bf16x8;
typedef __attribute__((ext_vector_type(8))) unsigned short u16x8;
typedef __attribute__((ext_vector_type(4))) float f32x4;

__device__ __forceinline__ void gld16(const void* g, void* l) {
    __builtin_amdgcn_global_load_lds((const __attribute__((address_space(1))) unsigned int*)g,
                                     (__attribute__((address_space(3))) unsigned int*)l,
                                     16, 0, 0);
}

__device__ __forceinline__ unsigned short f2bf_hi(float f) {
    unsigned u = __builtin_bit_cast(unsigned, f);
    u += 0x7FFF + ((u >> 16) & 1);
    return (unsigned short)(u >> 16);
}

// rne f32x8 -> bf16x8 (single-plane A convert at consume)
__device__ __forceinline__ bf16x8 rne8(f32x4 a, f32x4 b) {
    bf16x8 h;
    float f[8] = {a[0], a[1], a[2], a[3], b[0], b[1], b[2], b[3]};
#pragma unroll
    for (int e = 0; e < 8; e++) {
        unsigned u = __builtin_bit_cast(unsigned, f[e]);
        u += 0x7FFF + ((u >> 16) & 1);
        h[e] = (short)(u >> 16);
    }
    return h;
}

// ============ GEMM layer1: round-8 proven structure (95us), reverted after the
// barrier-free round-16 experiment regressed (134us: 1 block/CU + 4x B staging
// killed TLP; lock-step theory falsified). Triple-buffer {A,B} in LDS, stage(t+2)
// in iter t, counted vmcnt(3). ROUND-17 CHANGE: C output is f32 (no f2bf_hi) —
// the h-table feeds k_edge's VALU-bound gather loop; f32 storage removes the
// bf16->f32 unpack (8 shl per 4-edge-lane) there. Write traffic +25MB (~+5us).
__global__ __launch_bounds__(512) void k_gemm_f32A(const float* __restrict__ A,
                                                   const unsigned short* __restrict__ Bh,
                                                   float* __restrict__ Cf,
                                                   float* __restrict__ asrc,
                                                   float* __restrict__ adst,
                                                   const float* __restrict__ att_s,
                                                   const float* __restrict__ att_d,
                                                   int M, int K) {
    __shared__ char smem[73728];  // 3 bufs x 24576: {A 16K: 128B/row slot^=(r&7) | B 8K: 64B/row slot^=((r>>1)&3)}

    const int tid = threadIdx.x, lane = tid & 63, w = tid >> 6;  // w = 0..7
    const int m16 = lane & 15, q = lane >> 4;
    const int mq = w >> 1, nh = w & 1;   // wave owns 32 rows x 64 cols
    const int row0 = blockIdx.x * 128, col0 = blockIdx.y * 128;
    const int NT = K >> 5;

    f32x4 acc[2][4];
#pragma unroll
    for (int i = 0; i < 2; i++)
#pragma unroll
        for (int j = 0; j < 4; j++) acc[i][j] = (f32x4){0.f, 0.f, 0.f, 0.f};

    // A: 16 chunks of 1KB; wave w stages j = 2w..2w+1.
    // chunk j: lane l -> row r = j*8+(l>>3), phys slot p = l&7; src slot s = p ^ (r&7).
    const float* apt[2];
    const int jA0 = w * 2;
#pragma unroll
    for (int jj = 0; jj < 2; jj++) {
        int j = jA0 + jj;
        int r = j * 8 + (lane >> 3);
        int grow = row0 + r;
        if (grow > M - 1) grow = M - 1;
        int s = (lane & 7) ^ ((lane >> 3) & 7);
        apt[jj] = A + (size_t)grow * K + s * 4;
    }
    // B: 8 chunks of 1KB; wave w stages chunk w.
    // chunk j: lane l -> row r = j*16+(l>>2), phys slot p = l&3; src s = p ^ ((r>>1)&3).
    const unsigned short* bpt;
    {
        int r = w * 16 + (lane >> 2);
        int s = (lane & 3) ^ ((lane >> 3) & 3);
        bpt = Bh + (size_t)(col0 + r) * K + s * 8;
    }

    auto stage = [&](int t, int buf) {   // 3 gld16 per wave: B, A, A
        char* S = smem + buf * 24576;
        gld16(bpt + (size_t)t * 32, S + 16384 + w * 1024);
#pragma unroll
        for (int jj = 0; jj < 2; jj++)
            gld16(apt[jj] + (size_t)t * 32, S + (jA0 + jj) * 1024);
    };

    // prologue: buf0, buf1 staged; retire buf0 (leave buf1's 3 loads flying)
    stage(0, 0); SB0;
    stage(1, 1); SB0;
    asm volatile("s_waitcnt vmcnt(3)" ::: "memory");
    __builtin_amdgcn_s_barrier();

    for (int t = 0; t < NT; ++t) {
        if (t + 2 < NT) stage(t + 2, (t + 2) % 3);
        SB0;

        const char* S  = smem + (t % 3) * 24576;
        const char* A_ = S;
        const char* B_ = S + 16384;
        bf16x8 bh[4];
#pragma unroll
        for (int nt = 0; nt < 4; nt++) {
            int r = nh * 64 + nt * 16 + m16;
            int p = q ^ ((r >> 1) & 3);
            bh[nt] = *(const bf16x8*)(B_ + r * 64 + p * 16);
        }
#pragma unroll
        for (int mt = 0; mt < 2; mt++) {
            int r = mq * 32 + mt * 16 + m16;
            int p0 = (2 * q) ^ (r & 7);
            int p1 = (2 * q + 1) ^ (r & 7);
            f32x4 a0 = *(const f32x4*)(A_ + r * 128 + p0 * 16);
            f32x4 a1 = *(const f32x4*)(A_ + r * 128 + p1 * 16);
            bf16x8 ah = rne8(a0, a1);
#pragma unroll
            for (int nt = 0; nt < 4; nt++)
                acc[mt][nt] = __builtin_amdgcn_mfma_f32_16x16x32_bf16(ah, bh[nt], acc[mt][nt], 0, 0, 0);
        }
        SB0;
        // bottom of t: FIFO = [stage(t+1):3 (issued iter t-1), stage(t+2):3 (this iter)]
        if (t + 2 < NT) asm volatile("s_waitcnt vmcnt(3)" ::: "memory");
        else            asm volatile("s_waitcnt vmcnt(0)" ::: "memory");
        __builtin_amdgcn_s_barrier();
    }

    const int rbase = row0 + mq * 32;
    const int cbase = col0 + nh * 64;
#pragma unroll
    for (int mt = 0; mt < 2; mt++)
#pragma unroll
        for (int r = 0; r < 4; r++) {
            int row = rbase + mt * 16 + q * 4 + r;
            if (row < M) {
#pragma unroll
                for (int nt = 0; nt < 4; nt++)
                    Cf[(size_t)row * 256 + cbase + nt * 16 + m16] = acc[mt][nt][r];
            }
        }
    float as_v[4], ad_v[4];
#pragma unroll
    for (int nt = 0; nt < 4; nt++) {
        as_v[nt] = att_s[cbase + nt * 16 + m16];
        ad_v[nt] = att_d[cbase + nt * 16 + m16];
    }
#pragma unroll
    for (int mt = 0; mt < 2; mt++)
#pragma unroll
        for (int r = 0; r < 4; r++) {
            float s = 0.f, d = 0.f;
#pragma unroll
            for (int nt = 0; nt < 4; nt++) {
                float v = acc[mt][nt][r];
                s = fmaf(v, as_v[nt], s);
                d = fmaf(v, ad_v[nt], d);
            }
#pragma unroll
            for (int off = 1; off < 16; off <<= 1) {
                s += __shfl_xor(s, off);
                d += __shfl_xor(d, off);
            }
            int row = rbase + mt * 16 + q * 4 + r;
            if (m16 == 0 && row < M) {
                atomicAdd(&asrc[row], s);
                atomicAdd(&adst[row], d);
            }
        }
}

// ============ GEMM layer2: round-8 proven structure; C output f32 (round-17).
__global__ __launch_bounds__(512) void k_gemm_bf16A(const unsigned short* __restrict__ Ah,
                                                    const unsigned short* __restrict__ Bh,
                                                    float* __restrict__ Cf,
                                                    float* __restrict__ asrc,
                                                    float* __restrict__ adst,
                                                    const float* __restrict__ att_s,
                                                    const float* __restrict__ att_d,
                                                    int M, int K) {
    __shared__ char smem[49152];  // 3 bufs x 16384: {A 8K | B 8K}, both 64B/row slot^=((r>>1)&3)

    const int tid = threadIdx.x, lane = tid & 63, w = tid >> 6;
    const int m16 = lane & 15, q = lane >> 4;
    const int mq = w >> 1, nh = w & 1;
    const int row0 = blockIdx.x * 128, col0 = blockIdx.y * 128;
    const int NT = K >> 5;

    f32x4 acc[2][4];
#pragma unroll
    for (int i = 0; i < 2; i++)
#pragma unroll
        for (int j = 0; j < 4; j++) acc[i][j] = (f32x4){0.f, 0.f, 0.f, 0.f};

    // each plane: 8 chunks of 1KB; wave w stages chunk w.
    const unsigned short* ahpt;
    const unsigned short* bpt;
    {
        int r = w * 16 + (lane >> 2);
        int s = (lane & 3) ^ ((lane >> 3) & 3);
        ahpt = Ah + (size_t)(row0 + r) * K + s * 8;   // rows < Mpad: in-bounds workspace
        bpt  = Bh + (size_t)(col0 + r) * K + s * 8;
    }

    auto stage = [&](int t, int buf) {   // 2 gld16 per wave
        char* S = smem + buf * 16384;
        gld16(bpt  + (size_t)t * 32, S + 8192 + w * 1024);
        gld16(ahpt + (size_t)t * 32, S + w * 1024);
    };

    stage(0, 0); SB0;
    stage(1, 1); SB0;
    asm volatile("s_waitcnt vmcnt(2)" ::: "memory");
    __builtin_amdgcn_s_barrier();

    for (int t = 0; t < NT; ++t) {
        if (t + 2 < NT) stage(t + 2, (t + 2) % 3);
        SB0;

        const char* S   = smem + (t % 3) * 16384;
        const char* Ah_ = S;
        const char* B_  = S + 8192;
        bf16x8 bh[4];
#pragma unroll
        for (int nt = 0; nt < 4; nt++) {
            int r = nh * 64 + nt * 16 + m16;
            int p = q ^ ((r >> 1) & 3);
            bh[nt] = *(const bf16x8*)(B_ + r * 64 + p * 16);
        }
#pragma unroll
        for (int mt = 0; mt < 2; mt++) {
            int r = mq * 32 + mt * 16 + m16;
            int p = q ^ ((r >> 1) & 3);
            bf16x8 ah = *(const bf16x8*)(Ah_ + r * 64 + p * 16);
#pragma unroll
            for (int nt = 0; nt < 4; nt++)
                acc[mt][nt] = __builtin_amdgcn_mfma_f32_16x16x32_bf16(ah, bh[nt], acc[mt][nt], 0, 0, 0);
        }
        SB0;
        if (t + 2 < NT) asm volatile("s_waitcnt vmcnt(2)" ::: "memory");
        else            asm volatile("s_waitcnt vmcnt(0)" ::: "memory");
        __builtin_amdgcn_s_barrier();
    }

    const int rbase = row0 + mq * 32;
    const int cbase = col0 + nh * 64;
#pragma unroll
    for (int mt = 0; mt < 2; mt++)
#pragma unroll
        for (int r = 0; r < 4; r++) {
            int row = rbase + mt * 16 + q * 4 + r;
            if (row < M) {
#pragma unroll
                for (int nt = 0; nt < 4; nt++)
                    Cf[(size_t)row * 256 + cbase + nt * 16 + m16] = acc[mt][nt][r];
            }
        }
    float as_v[4], ad_v[4];
#pragma unroll
    for (int nt = 0; nt < 4; nt++) {
        as_v[nt] = att_s[cbase + nt * 16 + m16];
        ad_v[nt] = att_d[cbase + nt * 16 + m16];
    }
#pragma unroll
    for (int mt = 0; mt < 2; mt++)
#pragma unroll
        for (int r = 0; r < 4; r++) {
            float s = 0.f, d = 0.f;
#pragma unroll
            for (int nt = 0; nt < 4; nt++) {
                float v = acc[mt][nt][r];
                s = fmaf(v, as_v[nt], s);
                d = fmaf(v, ad_v[nt], d);
            }
#pragma unroll
            for (int off = 1; off < 16; off <<= 1) {
                s += __shfl_xor(s, off);
                d += __shfl_xor(d, off);
            }
            int row = rbase + mt * 16 + q * 4 + r;
            if (m16 == 0 && row < M) {
                atomicAdd(&asrc[row], s);
                atomicAdd(&adst[row], d);
            }
        }
}

// ---------------- W [K][256] fp32 -> BT [256][K] bf16 (transpose + rne round)
__global__ __launch_bounds__(256) void k_convB(const float* __restrict__ W,
                                               unsigned short* __restrict__ BThi, int K) {
    int idx = blockIdx.x * 256 + threadIdx.x;
    int k = idx >> 8, n = idx & 255;
    if (k >= K) return;
    BThi[(size_t)n * K + k] = f2bf_hi(W[(size_t)k * 256 + n]);
}

// ---------------- CSR build
__global__ __launch_bounds__(256) void k_degree(const int* __restrict__ dst,
                                                int* __restrict__ counts, int E) {
    int e = blockIdx.x * 256 + threadIdx.x;
    if (e < E) atomicAdd(&counts[dst[e]], 1);
}

__global__ __launch_bounds__(256) void k_part(const int* __restrict__ counts,
                                              int* __restrict__ psum, int N) {
    __shared__ int red[256];
    int tid = threadIdx.x;
    int i = blockIdx.x * 256 + tid;
    red[tid] = (i < N) ? counts[i] : 0;
    __syncthreads();
    for (int off = 128; off; off >>= 1) {
        if (tid < off) red[tid] += red[tid + off];
        __syncthreads();
    }
    if (tid == 0) psum[blockIdx.x] = red[0];
}

__global__ __launch_bounds__(256) void k_scan_part(int* __restrict__ psum, int nb,
                                                   int* __restrict__ total_out) {
    __shared__ int s[256];
    int tid = threadIdx.x;
    int v = (tid < nb) ? psum[tid] : 0;
    s[tid] = v;
    __syncthreads();
    for (int off = 1; off < 256; off <<= 1) {
        int t = (tid >= off) ? s[tid - off] : 0;
        __syncthreads();
        s[tid] += t;
        __syncthreads();
    }
    if (tid < nb) psum[tid] = s[tid] - v;
    if (tid == 255) *total_out = s[255];
}

__global__ __launch_bounds__(256) void k_rowptr(const int* __restrict__ counts,
                                                const int* __restrict__ psum,
                                                int* __restrict__ rowptr,
                                                int* __restrict__ cursor, int N) {
    __shared__ int s[256];
    int tid = threadIdx.x;
    int i = blockIdx.x * 256 + tid;
    int v = (i < N) ? counts[i] : 0;
    s[tid] = v;
    __syncthreads();
    for (int off = 1; off < 256; off <<= 1) {
        int t = (tid >= off) ? s[tid - off] : 0;
        __syncthreads();
        s[tid] += t;
        __syncthreads();
    }
    if (i < N) {
        int excl = psum[blockIdx.x] + s[tid] - v;
        rowptr[i] = excl;
        cursor[i] = excl;
    }
}

__global__ __launch_bounds__(256) void k_scatter(const int* __restrict__ src,
                                                 const int* __restrict__ dst,
                                                 int* __restrict__ cursor,
                                                 int* __restrict__ col, int E) {
    int e = blockIdx.x * 256 + threadIdx.x;
    if (e < E) {
        int p = atomicAdd(&cursor[dst[e]], 1);
        col[p] = src[e];
    }
}

// ---------------- single-pass softmax+gather, half-wave per node.
// Round-17: h-table is f32 (no bf16 unpack in the hot loop: was 8 shl per
// 4-edge-lane). Gathers are 2x float4 = 32B/lane, 1KB/edge contiguous; the
// 51MB table is L2/L3-resident so added bytes are cheap.
__global__ __launch_bounds__(256) void k_edge(const float* __restrict__ hb,
                                              const float* __restrict__ asrc,
                                              const float* __restrict__ adst,
                                              const float* __restrict__ gmaxv,
                                              const int* __restrict__ rowptr,
                                              const int* __restrict__ col,
                                              const float* __restrict__ bias,
                                              float* __restrict__ outf,
                                              unsigned short* __restrict__ outh,
                                              const float* __restrict__ gw,
                                              const float* __restrict__ gb,
                                              float* __restrict__ gatep, int N) {
    int hw = threadIdx.x >> 5;
    int l  = threadIdx.x & 31;
    int node = blockIdx.x * 8 + hw;
    if (node >= N) return;
    int j = rowptr[node], end = rowptr[node + 1];
    float ad = adst[node];
    float m = LRELU(gmaxv[0] + ad);

    float a[8];
    float wself = __expf(LRELU(asrc[node] + ad) - m);
    {
        float4 v0 = *(const float4*)&hb[(size_t)node * 256 + l * 8];
        float4 v1 = *(const float4*)&hb[(size_t)node * 256 + l * 8 + 4];
        a[0] = wself * v0.x; a[1] = wself * v0.y; a[2] = wself * v0.z; a[3] = wself * v0.w;
        a[4] = wself * v1.x; a[5] = wself * v1.y; a[6] = wself * v1.z; a[7] = wself * v1.w;
    }
    float denom = wself;

    for (; j + 4 <= end; j += 4) {
        int s0 = col[j], s1 = col[j + 1], s2 = col[j + 2], s3 = col[j + 3];
        float w0 = __expf(LRELU(asrc[s0] + ad) - m);
        float w1 = __expf(LRELU(asrc[s1] + ad) - m);
        float w2 = __expf(LRELU(asrc[s2] + ad) - m);
        float w3 = __expf(LRELU(asrc[s3] + ad) - m);
        denom += w0 + w1 + w2 + w3;
        float4 h0a = *(const float4*)&hb[(size_t)s0 * 256 + l * 8];
        float4 h0b = *(const float4*)&hb[(size_t)s0 * 256 + l * 8 + 4];
        float4 h1a = *(const float4*)&hb[(size_t)s1 * 256 + l * 8];
        float4 h1b = *(const float4*)&hb[(size_t)s1 * 256 + l * 8 + 4];
        float4 h2a = *(const float4*)&hb[(size_t)s2 * 256 + l * 8];
        float4 h2b = *(const float4*)&hb[(size_t)s2 * 256 + l * 8 + 4];
        float4 h3a = *(const float4*)&hb[(size_t)s3 * 256 + l * 8];
        float4 h3b = *(const float4*)&hb[(size_t)s3 * 256 + l * 8 + 4];
        a[0] = fmaf(w0, h0a.x, fmaf(w1, h1a.x, fmaf(w2, h2a.x, fmaf(w3, h3a.x, a[0]))));
        a[1] = fmaf(w0, h0a.y, fmaf(w1, h1a.y, fmaf(w2, h2a.y, fmaf(w3, h3a.y, a[1]))));
        a[2] = fmaf(w0, h0a.z, fmaf(w1, h1a.z, fmaf(w2, h2a.z, fmaf(w3, h3a.z, a[2]))));
        a[3] = fmaf(w0, h0a.w, fmaf(w1, h1a.w, fmaf(w2, h2a.w, fmaf(w3, h3a.w, a[3]))));
        a[4] = fmaf(w0, h0b.x, fmaf(w1, h1b.x, fmaf(w2, h2b.x, fmaf(w3, h3b.x, a[4]))));
        a[5] = fmaf(w0, h0b.y, fmaf(w1, h1b.y, fmaf(w2, h2b.y, fmaf(w3, h3b.y, a[5]))));
        a[6] = fmaf(w0, h0b.z, fmaf(w1, h1b.z, fmaf(w2, h2b.z, fmaf(w3, h3b.z, a[6]))));
        a[7] = fmaf(w0, h0b.w, fmaf(w1, h1b.w, fmaf(w2, h2b.w, fmaf(w3, h3b.w, a[7]))));
    }
    for (; j < end; j++) {
        int s = col[j];
        float wgt = __expf(LRELU(asrc[s] + ad) - m);
        denom += wgt;
        float4 ha = *(const float4*)&hb[(size_t)s * 256 + l * 8];
        float4 hbv = *(const float4*)&hb[(size_t)s * 256 + l * 8 + 4];
        a[0] = fmaf(wgt, ha.x, a[0]); a[1] = fmaf(wgt, ha.y, a[1]);
        a[2] = fmaf(wgt, ha.z, a[2]); a[3] = fmaf(wgt, ha.w, a[3]);
        a[4] = fmaf(wgt, hbv.x, a[4]); a[5] = fmaf(wgt, hbv.y, a[5]);
        a[6] = fmaf(wgt, hbv.z, a[6]); a[7] = fmaf(wgt, hbv.w, a[7]);
    }
    float inv = 1.0f / (denom + 1e-16f);
#pragma unroll
    for (int e = 0; e < 8; e++) a[e] *= inv;

    float o[8];
    {
        float4 bv0 = *(const float4*)&bias[l * 8];
        float4 bv1 = *(const float4*)&bias[l * 8 + 4];
        float bb[8] = {bv0.x, bv0.y, bv0.z, bv0.w, bv1.x, bv1.y, bv1.z, bv1.w};
#pragma unroll
        for (int e = 0; e < 8; e++) o[e] = fmaxf(a[e] + bb[e], 0.0f);
    }
    if (outf) {
        float4 o0 = make_float4(o[0], o[1], o[2], o[3]);
        float4 o1 = make_float4(o[4], o[5], o[6], o[7]);
        *(float4*)&outf[(size_t)node * 256 + l * 8]     = o0;
        *(float4*)&outf[(size_t)node * 256 + l * 8 + 4] = o1;
    }
    if (outh) {
        u16x8 ph;
#pragma unroll
        for (int e = 0; e < 8; e++) ph[e] = f2bf_hi(o[e]);
        *(u16x8*)&outh[(size_t)node * 256 + l * 8] = ph;
    }
    if (gatep) {
        float s = 0.f;
#pragma unroll
        for (int e = 0; e < 8; e++) s = fmaf(o[e], gw[l * 8 + e], s);
#pragma unroll
        for (int off = 16; off; off >>= 1) s += __shfl_xor(s, off);
        if (l == 0) gatep[node] = s + gb[0];
    }
}

// ---------------- reductions
__global__ __launch_bounds__(256) void k_pmax(const float* __restrict__ v, int N,
                                              float* __restrict__ pmax) {
    __shared__ float red[256];
    int tid = threadIdx.x;
    float m = -3.0e38f;
    for (int i = blockIdx.x * 256 + tid; i < N; i += gridDim.x * 256) m = fmaxf(m, v[i]);
    red[tid] = m;
    __syncthreads();
    for (int off = 128; off; off >>= 1) {
        if (tid < off) red[tid] = fmaxf(red[tid], red[tid + off]);
        __syncthreads();
    }
    if (tid == 0) pmax[blockIdx.x] = red[0];
}

__global__ __launch_bounds__(64) void k_fold(const float* __restrict__ p,
                                             float* __restrict__ o) {
    int lane = threadIdx.x;
    float m = p[lane];
#pragma unroll
    for (int off = 32; off; off >>= 1) m = fmaxf(m, __shfl_xor(m, off));
    if (lane == 0) o[0] = m;
}

__global__ __launch_bounds__(256) void k_gmid(const float* __restrict__ pmax, int nb,
                                              float* __restrict__ scal,
                                              float* __restrict__ gout) {
    __shared__ float red[256];
    int tid = threadIdx.x;
    red[tid] = (tid < nb) ? pmax[tid] : -3.0e38f;
    __syncthreads();
    for (int off = 128; off; off >>= 1) {
        if (tid < off) red[tid] = fmaxf(red[tid], red[tid + off]);
        __syncthreads();
    }
    if (tid == 0) { scal[0] = red[0]; scal[1] = 0.0f; }
    gout[tid] = 0.0f;
}

__global__ __launch_bounds__(256) void k_gout(const float* __restrict__ h,
                                              const float* __restrict__ gate,
                                              float* __restrict__ scal_rw,
                                              float* __restrict__ gout, int N) {
    int f = threadIdx.x;
    float gmax = scal_rw[0];
    float acc = 0.0f, sumw = 0.0f;
    for (int i = blockIdx.x; i < N; i += gridDim.x) {
        float w = __expf(gate[i] - gmax);
        acc = fmaf(w, h[(size_t)i * 256 + f], acc);
        sumw += w;
    }
    atomicAdd(&gout[f], acc);
    if (f == 0) atomicAdd(&scal_rw[1], sumw);
}

__global__ __launch_bounds__(256) void k_final(const float* __restrict__ gout,
                                               const float* __restrict__ scal,
                                               float* __restrict__ out) {
    int f = threadIdx.x;
    out[f] = gout[f] / scal[1];
}

extern "C" void kernel_launch(void* const* d_in, const int* in_sizes, int n_in,
                              void* d_out, int out_size, void* d_ws, size_t ws_size,
                              hipStream_t stream) {
    const float* x   = (const float*)d_in[0];
    const int*   ei  = (const int*)d_in[1];
    const float* W1  = (const float*)d_in[2];
    const float* b1  = (const float*)d_in[3];
    const float* as1 = (const float*)d_in[4];
    const float* ad1 = (const float*)d_in[5];
    const float* W2  = (const float*)d_in[6];
    const float* b2  = (const float*)d_in[7];
    const float* as2 = (const float*)d_in[8];
    const float* ad2 = (const float*)d_in[9];
    const float* gw  = (const float*)d_in[10];
    const float* gb  = (const float*)d_in[11];
    float* out = (float*)d_out;

    const int N = in_sizes[0] / 768;   // 50000
    const int E = in_sizes[1] / 2;     // 800000
    const int Mpad = (N + 127) & ~127; // 50048
    const int* srcA = ei;
    const int* dstA = ei + E;

    char* w = (char*)d_ws;
    auto alloc = [&](size_t bytes) -> void* {
        void* p = (void*)w;
        w += (bytes + 255) & ~(size_t)255;
        return p;
    };
    float* bufHf = (float*)alloc((size_t)Mpad * 256 * 4);     // f32 h-table (both layers)
    float* bufX = (float*)alloc((size_t)Mpad * 256 * 4);      // f32 h2 (layer-2 output)
    unsigned short* X2h = (unsigned short*)bufX;              // alias: bf16 X2 plane, dead before bufX written
    float* asrc   = (float*)alloc((size_t)N * 4);
    float* adst   = (float*)alloc((size_t)N * 4);
    float* gate   = (float*)alloc((size_t)N * 4);
    int*   counts = (int*)alloc((size_t)N * 4);
    int*   rowptr = (int*)alloc((size_t)(N + 1) * 4);
    int*   cursor = (int*)alloc((size_t)N * 4);
    int*   colbuf = (int*)alloc((size_t)E * 4);
    int*   psum   = (int*)alloc(256 * 4);
    float* pmax   = (float*)alloc(256 * 4);
    float* gmaxv  = (float*)alloc(4 * 4);
    float* scal   = (float*)alloc(8 * 4);
    float* gout   = (float*)alloc(256 * 4);
    unsigned short* BT1 = (unsigned short*)alloc((size_t)256 * 768 * 2);
    unsigned short* BT2 = (unsigned short*)alloc((size_t)256 * 256 * 2);

    const int eb  = (E + 255) / 256;
    const int nb8 = (N + 7) / 8;
    const int nb  = (N + 255) / 256;
    const dim3 gg(Mpad / 128, 2);

    // weight transpose + rne-bf16 (single plane)
    k_convB<<<768, 256, 0, stream>>>(W1, BT1, 768);
    k_convB<<<256, 256, 0, stream>>>(W2, BT2, 256);

    // CSR by dst
    (void)hipMemsetAsync(counts, 0, (size_t)N * 4, stream);
    k_degree<<<eb, 256, 0, stream>>>(dstA, counts, E);
    k_part<<<nb, 256, 0, stream>>>(counts, psum, N);
    k_scan_part<<<1, 256, 0, stream>>>(psum, nb, rowptr + N);
    k_rowptr<<<nb, 256, 0, stream>>>(counts, psum, rowptr, cursor, N);
    k_scatter<<<eb, 256, 0, stream>>>(srcA, dstA, cursor, colbuf, E);

    // layer 1
    (void)hipMemsetAsync(asrc, 0, (size_t)N * 4, stream);
    (void)hipMemsetAsync(adst, 0, (size_t)N * 4, stream);
    k_gemm_f32A<<<gg, 512, 0, stream>>>(x, BT1, bufHf, asrc, adst, as1, ad1, N, 768);
    k_pmax<<<64, 256, 0, stream>>>(asrc, N, pmax);
    k_fold<<<1, 64, 0, stream>>>(pmax, gmaxv);
    k_edge<<<nb8, 256, 0, stream>>>(bufHf, asrc, adst, gmaxv, rowptr, colbuf, b1,
                                    nullptr, X2h, nullptr, nullptr, nullptr, N);

    // layer 2
    (void)hipMemsetAsync(asrc, 0, (size_t)N * 4, stream);
    (void)hipMemsetAsync(adst, 0, (size_t)N * 4, stream);
    k_gemm_bf16A<<<gg, 512, 0, stream>>>(X2h, BT2, bufHf, asrc, adst, as2, ad2, N, 256);
    k_pmax<<<64, 256, 0, stream>>>(asrc, N, pmax);
    k_fold<<<1, 64, 0, stream>>>(pmax, gmaxv);
    k_edge<<<nb8, 256, 0, stream>>>(bufHf, asrc, adst, gmaxv, rowptr, colbuf, b2,
                                    bufX, nullptr, gw, gb, gate, N);

    // global attention
    k_pmax<<<64, 256, 0, stream>>>(gate, N, pmax);
    k_gmid<<<1, 256, 0, stream>>>(pmax, 64, scal, gout);
    k_gout<<<256, 256, 0, stream>>>(bufX, gate, scal, gout, N);
    k_final<<<1, 256, 0, stream>>>(gout, scal, out);
}

// Round 12
// 584.084 us; speedup vs baseline: 1.2062x; 1.2062x over previous
//
#include <hip/hip_runtime.h>

#define WAVE 64
#define LRELU(x) ((x) > 0.0f ? (x) : 0.2f * (x))
#define SB0 __builtin_amdgcn_sched_barrier(0)

typedef __attribute__((ext_vector_type(8))) short bf16x8;
typedef __attribute__((ext_vector_type(8))) unsigned short u16x8;
typedef __attribute__((ext_vector_type(4))) float f32x4;

__device__ __forceinline__ void gld16(const void* g, void* l) {
    __builtin_amdgcn_global_load_lds((const __attribute__((address_space(1))) unsigned int*)g,
                                     (__attribute__((address_space(3))) unsigned int*)l,
                                     16, 0, 0);
}

__device__ __forceinline__ unsigned short f2bf_hi(float f) {
    unsigned u = __builtin_bit_cast(unsigned, f);
    u += 0x7FFF + ((u >> 16) & 1);
    return (unsigned short)(u >> 16);
}

__device__ __forceinline__ float bf2f(unsigned short h) {
    return __builtin_bit_cast(float, (unsigned)h << 16);
}

// rne f32x8 -> bf16x8 (single-plane A convert at consume)
__device__ __forceinline__ bf16x8 rne8(f32x4 a, f32x4 b) {
    bf16x8 h;
    float f[8] = {a[0], a[1], a[2], a[3], b[0], b[1], b[2], b[3]};
#pragma unroll
    for (int e = 0; e < 8; e++) {
        unsigned u = __builtin_bit_cast(unsigned, f[e]);
        u += 0x7FFF + ((u >> 16) & 1);
        h[e] = (short)(u >> 16);
    }
    return h;
}

// ============ GEMM layer1: round-8 proven structure (95us, 588 total).
// Round-17's f32 C-table regressed k_edge (gather bytes doubled; k_edge is
// gather-BW-bound, NOT VALU-bound) -> reverted to bf16 C output.
__global__ __launch_bounds__(512) void k_gemm_f32A(const float* __restrict__ A,
                                                   const unsigned short* __restrict__ Bh,
                                                   unsigned short* __restrict__ Cb,
                                                   float* __restrict__ asrc,
                                                   float* __restrict__ adst,
                                                   const float* __restrict__ att_s,
                                                   const float* __restrict__ att_d,
                                                   int M, int K) {
    __shared__ char smem[73728];  // 3 bufs x 24576: {A 16K: 128B/row slot^=(r&7) | B 8K: 64B/row slot^=((r>>1)&3)}

    const int tid = threadIdx.x, lane = tid & 63, w = tid >> 6;  // w = 0..7
    const int m16 = lane & 15, q = lane >> 4;
    const int mq = w >> 1, nh = w & 1;   // wave owns 32 rows x 64 cols
    const int row0 = blockIdx.x * 128, col0 = blockIdx.y * 128;
    const int NT = K >> 5;

    f32x4 acc[2][4];
#pragma unroll
    for (int i = 0; i < 2; i++)
#pragma unroll
        for (int j = 0; j < 4; j++) acc[i][j] = (f32x4){0.f, 0.f, 0.f, 0.f};

    // A: 16 chunks of 1KB; wave w stages j = 2w..2w+1.
    const float* apt[2];
    const int jA0 = w * 2;
#pragma unroll
    for (int jj = 0; jj < 2; jj++) {
        int j = jA0 + jj;
        int r = j * 8 + (lane >> 3);
        int grow = row0 + r;
        if (grow > M - 1) grow = M - 1;
        int s = (lane & 7) ^ ((lane >> 3) & 7);
        apt[jj] = A + (size_t)grow * K + s * 4;
    }
    // B: 8 chunks of 1KB; wave w stages chunk w.
    const unsigned short* bpt;
    {
        int r = w * 16 + (lane >> 2);
        int s = (lane & 3) ^ ((lane >> 3) & 3);
        bpt = Bh + (size_t)(col0 + r) * K + s * 8;
    }

    auto stage = [&](int t, int buf) {   // 3 gld16 per wave: B, A, A
        char* S = smem + buf * 24576;
        gld16(bpt + (size_t)t * 32, S + 16384 + w * 1024);
#pragma unroll
        for (int jj = 0; jj < 2; jj++)
            gld16(apt[jj] + (size_t)t * 32, S + (jA0 + jj) * 1024);
    };

    stage(0, 0); SB0;
    stage(1, 1); SB0;
    asm volatile("s_waitcnt vmcnt(3)" ::: "memory");
    __builtin_amdgcn_s_barrier();

    for (int t = 0; t < NT; ++t) {
        if (t + 2 < NT) stage(t + 2, (t + 2) % 3);
        SB0;

        const char* S  = smem + (t % 3) * 24576;
        const char* A_ = S;
        const char* B_ = S + 16384;
        bf16x8 bh[4];
#pragma unroll
        for (int nt = 0; nt < 4; nt++) {
            int r = nh * 64 + nt * 16 + m16;
            int p = q ^ ((r >> 1) & 3);
            bh[nt] = *(const bf16x8*)(B_ + r * 64 + p * 16);
        }
#pragma unroll
        for (int mt = 0; mt < 2; mt++) {
            int r = mq * 32 + mt * 16 + m16;
            int p0 = (2 * q) ^ (r & 7);
            int p1 = (2 * q + 1) ^ (r & 7);
            f32x4 a0 = *(const f32x4*)(A_ + r * 128 + p0 * 16);
            f32x4 a1 = *(const f32x4*)(A_ + r * 128 + p1 * 16);
            bf16x8 ah = rne8(a0, a1);
#pragma unroll
            for (int nt = 0; nt < 4; nt++)
                acc[mt][nt] = __builtin_amdgcn_mfma_f32_16x16x32_bf16(ah, bh[nt], acc[mt][nt], 0, 0, 0);
        }
        SB0;
        if (t + 2 < NT) asm volatile("s_waitcnt vmcnt(3)" ::: "memory");
        else            asm volatile("s_waitcnt vmcnt(0)" ::: "memory");
        __builtin_amdgcn_s_barrier();
    }

    const int rbase = row0 + mq * 32;
    const int cbase = col0 + nh * 64;
#pragma unroll
    for (int mt = 0; mt < 2; mt++)
#pragma unroll
        for (int r = 0; r < 4; r++) {
            int row = rbase + mt * 16 + q * 4 + r;
            if (row < M) {
#pragma unroll
                for (int nt = 0; nt < 4; nt++)
                    Cb[(size_t)row * 256 + cbase + nt * 16 + m16] = f2bf_hi(acc[mt][nt][r]);
            }
        }
    float as_v[4], ad_v[4];
#pragma unroll
    for (int nt = 0; nt < 4; nt++) {
        as_v[nt] = att_s[cbase + nt * 16 + m16];
        ad_v[nt] = att_d[cbase + nt * 16 + m16];
    }
#pragma unroll
    for (int mt = 0; mt < 2; mt++)
#pragma unroll
        for (int r = 0; r < 4; r++) {
            float s = 0.f, d = 0.f;
#pragma unroll
            for (int nt = 0; nt < 4; nt++) {
                float v = acc[mt][nt][r];
                s = fmaf(v, as_v[nt], s);
                d = fmaf(v, ad_v[nt], d);
            }
#pragma unroll
            for (int off = 1; off < 16; off <<= 1) {
                s += __shfl_xor(s, off);
                d += __shfl_xor(d, off);
            }
            int row = rbase + mt * 16 + q * 4 + r;
            if (m16 == 0 && row < M) {
                atomicAdd(&asrc[row], s);
                atomicAdd(&adst[row], d);
            }
        }
}

// ============ GEMM layer2: single bf16 A plane, counted-vmcnt triple-buffer.
__global__ __launch_bounds__(512) void k_gemm_bf16A(const unsigned short* __restrict__ Ah,
                                                    const unsigned short* __restrict__ Bh,
                                                    unsigned short* __restrict__ Cb,
                                                    float* __restrict__ asrc,
                                                    float* __restrict__ adst,
                                                    const float* __restrict__ att_s,
                                                    const float* __restrict__ att_d,
                                                    int M, int K) {
    __shared__ char smem[49152];  // 3 bufs x 16384: {A 8K | B 8K}, both 64B/row slot^=((r>>1)&3)

    const int tid = threadIdx.x, lane = tid & 63, w = tid >> 6;
    const int m16 = lane & 15, q = lane >> 4;
    const int mq = w >> 1, nh = w & 1;
    const int row0 = blockIdx.x * 128, col0 = blockIdx.y * 128;
    const int NT = K >> 5;

    f32x4 acc[2][4];
#pragma unroll
    for (int i = 0; i < 2; i++)
#pragma unroll
        for (int j = 0; j < 4; j++) acc[i][j] = (f32x4){0.f, 0.f, 0.f, 0.f};

    const unsigned short* ahpt;
    const unsigned short* bpt;
    {
        int r = w * 16 + (lane >> 2);
        int s = (lane & 3) ^ ((lane >> 3) & 3);
        ahpt = Ah + (size_t)(row0 + r) * K + s * 8;   // rows < Mpad: in-bounds workspace
        bpt  = Bh + (size_t)(col0 + r) * K + s * 8;
    }

    auto stage = [&](int t, int buf) {   // 2 gld16 per wave
        char* S = smem + buf * 16384;
        gld16(bpt  + (size_t)t * 32, S + 8192 + w * 1024);
        gld16(ahpt + (size_t)t * 32, S + w * 1024);
    };

    stage(0, 0); SB0;
    stage(1, 1); SB0;
    asm volatile("s_waitcnt vmcnt(2)" ::: "memory");
    __builtin_amdgcn_s_barrier();

    for (int t = 0; t < NT; ++t) {
        if (t + 2 < NT) stage(t + 2, (t + 2) % 3);
        SB0;

        const char* S   = smem + (t % 3) * 16384;
        const char* Ah_ = S;
        const char* B_  = S + 8192;
        bf16x8 bh[4];
#pragma unroll
        for (int nt = 0; nt < 4; nt++) {
            int r = nh * 64 + nt * 16 + m16;
            int p = q ^ ((r >> 1) & 3);
            bh[nt] = *(const bf16x8*)(B_ + r * 64 + p * 16);
        }
#pragma unroll
        for (int mt = 0; mt < 2; mt++) {
            int r = mq * 32 + mt * 16 + m16;
            int p = q ^ ((r >> 1) & 3);
            bf16x8 ah = *(const bf16x8*)(Ah_ + r * 64 + p * 16);
#pragma unroll
            for (int nt = 0; nt < 4; nt++)
                acc[mt][nt] = __builtin_amdgcn_mfma_f32_16x16x32_bf16(ah, bh[nt], acc[mt][nt], 0, 0, 0);
        }
        SB0;
        if (t + 2 < NT) asm volatile("s_waitcnt vmcnt(2)" ::: "memory");
        else            asm volatile("s_waitcnt vmcnt(0)" ::: "memory");
        __builtin_amdgcn_s_barrier();
    }

    const int rbase = row0 + mq * 32;
    const int cbase = col0 + nh * 64;
#pragma unroll
    for (int mt = 0; mt < 2; mt++)
#pragma unroll
        for (int r = 0; r < 4; r++) {
            int row = rbase + mt * 16 + q * 4 + r;
            if (row < M) {
#pragma unroll
                for (int nt = 0; nt < 4; nt++)
                    Cb[(size_t)row * 256 + cbase + nt * 16 + m16] = f2bf_hi(acc[mt][nt][r]);
            }
        }
    float as_v[4], ad_v[4];
#pragma unroll
    for (int nt = 0; nt < 4; nt++) {
        as_v[nt] = att_s[cbase + nt * 16 + m16];
        ad_v[nt] = att_d[cbase + nt * 16 + m16];
    }
#pragma unroll
    for (int mt = 0; mt < 2; mt++)
#pragma unroll
        for (int r = 0; r < 4; r++) {
            float s = 0.f, d = 0.f;
#pragma unroll
            for (int nt = 0; nt < 4; nt++) {
                float v = acc[mt][nt][r];
                s = fmaf(v, as_v[nt], s);
                d = fmaf(v, ad_v[nt], d);
            }
#pragma unroll
            for (int off = 1; off < 16; off <<= 1) {
                s += __shfl_xor(s, off);
                d += __shfl_xor(d, off);
            }
            int row = rbase + mt * 16 + q * 4 + r;
            if (m16 == 0 && row < M) {
                atomicAdd(&asrc[row], s);
                atomicAdd(&adst[row], d);
            }
        }
}

// ---------------- W [K][256] fp32 -> BT [256][K] bf16 (transpose + rne round)
__global__ __launch_bounds__(256) void k_convB(const float* __restrict__ W,
                                               unsigned short* __restrict__ BThi, int K) {
    int idx = blockIdx.x * 256 + threadIdx.x;
    int k = idx >> 8, n = idx & 255;
    if (k >= K) return;
    BThi[(size_t)n * K + k] = f2bf_hi(W[(size_t)k * 256 + n]);
}

// ---------------- CSR build
__global__ __launch_bounds__(256) void k_degree(const int* __restrict__ dst,
                                                int* __restrict__ counts, int E) {
    int e = blockIdx.x * 256 + threadIdx.x;
    if (e < E) atomicAdd(&counts[dst[e]], 1);
}

__global__ __launch_bounds__(256) void k_part(const int* __restrict__ counts,
                                              int* __restrict__ psum, int N) {
    __shared__ int red[256];
    int tid = threadIdx.x;
    int i = blockIdx.x * 256 + tid;
    red[tid] = (i < N) ? counts[i] : 0;
    __syncthreads();
    for (int off = 128; off; off >>= 1) {
        if (tid < off) red[tid] += red[tid + off];
        __syncthreads();
    }
    if (tid == 0) psum[blockIdx.x] = red[0];
}

__global__ __launch_bounds__(256) void k_scan_part(int* __restrict__ psum, int nb,
                                                   int* __restrict__ total_out) {
    __shared__ int s[256];
    int tid = threadIdx.x;
    int v = (tid < nb) ? psum[tid] : 0;
    s[tid] = v;
    __syncthreads();
    for (int off = 1; off < 256; off <<= 1) {
        int t = (tid >= off) ? s[tid - off] : 0;
        __syncthreads();
        s[tid] += t;
        __syncthreads();
    }
    if (tid < nb) psum[tid] = s[tid] - v;
    if (tid == 255) *total_out = s[255];
}

__global__ __launch_bounds__(256) void k_rowptr(const int* __restrict__ counts,
                                                const int* __restrict__ psum,
                                                int* __restrict__ rowptr,
                                                int* __restrict__ cursor, int N) {
    __shared__ int s[256];
    int tid = threadIdx.x;
    int i = blockIdx.x * 256 + tid;
    int v = (i < N) ? counts[i] : 0;
    s[tid] = v;
    __syncthreads();
    for (int off = 1; off < 256; off <<= 1) {
        int t = (tid >= off) ? s[tid - off] : 0;
        __syncthreads();
        s[tid] += t;
        __syncthreads();
    }
    if (i < N) {
        int excl = psum[blockIdx.x] + s[tid] - v;
        rowptr[i] = excl;
        cursor[i] = excl;
    }
}

__global__ __launch_bounds__(256) void k_scatter(const int* __restrict__ src,
                                                 const int* __restrict__ dst,
                                                 int* __restrict__ cursor,
                                                 int* __restrict__ col, int E) {
    int e = blockIdx.x * 256 + threadIdx.x;
    if (e < E) {
        int p = atomicAdd(&cursor[dst[e]], 1);
        col[p] = src[e];
    }
}

// ---------------- single-pass softmax+gather, half-wave per node.
// Round-18: k_edge is gather-latency/BW-bound (round-17 PMC: 47% fetch, 15%
// VALU). bf16 table (min bytes) + 8-EDGE UNROLL -> 16 outstanding 16B gathers
// per half-wave stream (was 8), doubling memory-level parallelism per stream.
__global__ __launch_bounds__(256) void k_edge(const unsigned short* __restrict__ hb,
                                              const float* __restrict__ asrc,
                                              const float* __restrict__ adst,
                                              const float* __restrict__ gmaxv,
                                              const int* __restrict__ rowptr,
                                              const int* __restrict__ col,
                                              const float* __restrict__ bias,
                                              float* __restrict__ outf,
                                              unsigned short* __restrict__ outh,
                                              const float* __restrict__ gw,
                                              const float* __restrict__ gb,
                                              float* __restrict__ gatep, int N) {
    int hw = threadIdx.x >> 5;
    int l  = threadIdx.x & 31;
    int node = blockIdx.x * 8 + hw;
    if (node >= N) return;
    int j = rowptr[node], end = rowptr[node + 1];
    float ad = adst[node];
    float m = LRELU(gmaxv[0] + ad);

    float a[8];
    float wself = __expf(LRELU(asrc[node] + ad) - m);
    u16x8 hv = *(const u16x8*)&hb[(size_t)node * 256 + l * 8];
#pragma unroll
    for (int e = 0; e < 8; e++) a[e] = wself * bf2f(hv[e]);
    float denom = wself;

    for (; j + 8 <= end; j += 8) {
        int s0 = col[j],     s1 = col[j + 1], s2 = col[j + 2], s3 = col[j + 3];
        int s4 = col[j + 4], s5 = col[j + 5], s6 = col[j + 6], s7 = col[j + 7];
        u16x8 h0 = *(const u16x8*)&hb[(size_t)s0 * 256 + l * 8];
        u16x8 h1 = *(const u16x8*)&hb[(size_t)s1 * 256 + l * 8];
        u16x8 h2 = *(const u16x8*)&hb[(size_t)s2 * 256 + l * 8];
        u16x8 h3 = *(const u16x8*)&hb[(size_t)s3 * 256 + l * 8];
        u16x8 h4 = *(const u16x8*)&hb[(size_t)s4 * 256 + l * 8];
        u16x8 h5 = *(const u16x8*)&hb[(size_t)s5 * 256 + l * 8];
        u16x8 h6 = *(const u16x8*)&hb[(size_t)s6 * 256 + l * 8];
        u16x8 h7 = *(const u16x8*)&hb[(size_t)s7 * 256 + l * 8];
        float w0 = __expf(LRELU(asrc[s0] + ad) - m);
        float w1 = __expf(LRELU(asrc[s1] + ad) - m);
        float w2 = __expf(LRELU(asrc[s2] + ad) - m);
        float w3 = __expf(LRELU(asrc[s3] + ad) - m);
        float w4 = __expf(LRELU(asrc[s4] + ad) - m);
        float w5 = __expf(LRELU(asrc[s5] + ad) - m);
        float w6 = __expf(LRELU(asrc[s6] + ad) - m);
        float w7 = __expf(LRELU(asrc[s7] + ad) - m);
        denom += w0 + w1 + w2 + w3 + w4 + w5 + w6 + w7;
#pragma unroll
        for (int e = 0; e < 8; e++) {
            float t0 = fmaf(w0, bf2f(h0[e]), fmaf(w1, bf2f(h1[e]),
                       fmaf(w2, bf2f(h2[e]), fmaf(w3, bf2f(h3[e]), a[e]))));
            a[e] = fmaf(w4, bf2f(h4[e]), fmaf(w5, bf2f(h5[e]),
                   fmaf(w6, bf2f(h6[e]), fmaf(w7, bf2f(h7[e]), t0))));
        }
    }
    for (; j + 4 <= end; j += 4) {
        int s0 = col[j], s1 = col[j + 1], s2 = col[j + 2], s3 = col[j + 3];
        u16x8 h0 = *(const u16x8*)&hb[(size_t)s0 * 256 + l * 8];
        u16x8 h1 = *(const u16x8*)&hb[(size_t)s1 * 256 + l * 8];
        u16x8 h2 = *(const u16x8*)&hb[(size_t)s2 * 256 + l * 8];
        u16x8 h3 = *(const u16x8*)&hb[(size_t)s3 * 256 + l * 8];
        float w0 = __expf(LRELU(asrc[s0] + ad) - m);
        float w1 = __expf(LRELU(asrc[s1] + ad) - m);
        float w2 = __expf(LRELU(asrc[s2] + ad) - m);
        float w3 = __expf(LRELU(asrc[s3] + ad) - m);
        denom += w0 + w1 + w2 + w3;
#pragma unroll
        for (int e = 0; e < 8; e++)
            a[e] = fmaf(w0, bf2f(h0[e]), fmaf(w1, bf2f(h1[e]),
                   fmaf(w2, bf2f(h2[e]), fmaf(w3, bf2f(h3[e]), a[e]))));
    }
    for (; j < end; j++) {
        int s = col[j];
        float wgt = __expf(LRELU(asrc[s] + ad) - m);
        denom += wgt;
        u16x8 hx = *(const u16x8*)&hb[(size_t)s * 256 + l * 8];
#pragma unroll
        for (int e = 0; e < 8; e++) a[e] = fmaf(wgt, bf2f(hx[e]), a[e]);
    }
    float inv = 1.0f / (denom + 1e-16f);
#pragma unroll
    for (int e = 0; e < 8; e++) a[e] *= inv;

    float o[8];
    {
        float4 bv0 = *(const float4*)&bias[l * 8];
        float4 bv1 = *(const float4*)&bias[l * 8 + 4];
        float bb[8] = {bv0.x, bv0.y, bv0.z, bv0.w, bv1.x, bv1.y, bv1.z, bv1.w};
#pragma unroll
        for (int e = 0; e < 8; e++) o[e] = fmaxf(a[e] + bb[e], 0.0f);
    }
    if (outf) {
        float4 o0 = make_float4(o[0], o[1], o[2], o[3]);
        float4 o1 = make_float4(o[4], o[5], o[6], o[7]);
        *(float4*)&outf[(size_t)node * 256 + l * 8]     = o0;
        *(float4*)&outf[(size_t)node * 256 + l * 8 + 4] = o1;
    }
    if (outh) {
        u16x8 ph;
#pragma unroll
        for (int e = 0; e < 8; e++) ph[e] = f2bf_hi(o[e]);
        *(u16x8*)&outh[(size_t)node * 256 + l * 8] = ph;
    }
    if (gatep) {
        float s = 0.f;
#pragma unroll
        for (int e = 0; e < 8; e++) s = fmaf(o[e], gw[l * 8 + e], s);
#pragma unroll
        for (int off = 16; off; off >>= 1) s += __shfl_xor(s, off);
        if (l == 0) gatep[node] = s + gb[0];
    }
}

// ---------------- reductions
__global__ __launch_bounds__(256) void k_pmax(const float* __restrict__ v, int N,
                                              float* __restrict__ pmax) {
    __shared__ float red[256];
    int tid = threadIdx.x;
    float m = -3.0e38f;
    for (int i = blockIdx.x * 256 + tid; i < N; i += gridDim.x * 256) m = fmaxf(m, v[i]);
    red[tid] = m;
    __syncthreads();
    for (int off = 128; off; off >>= 1) {
        if (tid < off) red[tid] = fmaxf(red[tid], red[tid + off]);
        __syncthreads();
    }
    if (tid == 0) pmax[blockIdx.x] = red[0];
}

__global__ __launch_bounds__(64) void k_fold(const float* __restrict__ p,
                                             float* __restrict__ o) {
    int lane = threadIdx.x;
    float m = p[lane];
#pragma unroll
    for (int off = 32; off; off >>= 1) m = fmaxf(m, __shfl_xor(m, off));
    if (lane == 0) o[0] = m;
}

__global__ __launch_bounds__(256) void k_gmid(const float* __restrict__ pmax, int nb,
                                              float* __restrict__ scal,
                                              float* __restrict__ gout) {
    __shared__ float red[256];
    int tid = threadIdx.x;
    red[tid] = (tid < nb) ? pmax[tid] : -3.0e38f;
    __syncthreads();
    for (int off = 128; off; off >>= 1) {
        if (tid < off) red[tid] = fmaxf(red[tid], red[tid + off]);
        __syncthreads();
    }
    if (tid == 0) { scal[0] = red[0]; scal[1] = 0.0f; }
    gout[tid] = 0.0f;
}

__global__ __launch_bounds__(256) void k_gout(const float* __restrict__ h,
                                              const float* __restrict__ gate,
                                              float* __restrict__ scal_rw,
                                              float* __restrict__ gout, int N) {
    int f = threadIdx.x;
    float gmax = scal_rw[0];
    float acc = 0.0f, sumw = 0.0f;
    for (int i = blockIdx.x; i < N; i += gridDim.x) {
        float w = __expf(gate[i] - gmax);
        acc = fmaf(w, h[(size_t)i * 256 + f], acc);
        sumw += w;
    }
    atomicAdd(&gout[f], acc);
    if (f == 0) atomicAdd(&scal_rw[1], sumw);
}

__global__ __launch_bounds__(256) void k_final(const float* __restrict__ gout,
                                               const float* __restrict__ scal,
                                               float* __restrict__ out) {
    int f = threadIdx.x;
    out[f] = gout[f] / scal[1];
}

extern "C" void kernel_launch(void* const* d_in, const int* in_sizes, int n_in,
                              void* d_out, int out_size, void* d_ws, size_t ws_size,
                              hipStream_t stream) {
    const float* x   = (const float*)d_in[0];
    const int*   ei  = (const int*)d_in[1];
    const float* W1  = (const float*)d_in[2];
    const float* b1  = (const float*)d_in[3];
    const float* as1 = (const float*)d_in[4];
    const float* ad1 = (const float*)d_in[5];
    const float* W2  = (const float*)d_in[6];
    const float* b2  = (const float*)d_in[7];
    const float* as2 = (const float*)d_in[8];
    const float* ad2 = (const float*)d_in[9];
    const float* gw  = (const float*)d_in[10];
    const float* gb  = (const float*)d_in[11];
    float* out = (float*)d_out;

    const int N = in_sizes[0] / 768;   // 50000
    const int E = in_sizes[1] / 2;     // 800000
    const int Mpad = (N + 127) & ~127; // 50048
    const int* srcA = ei;
    const int* dstA = ei + E;

    char* w = (char*)d_ws;
    auto alloc = [&](size_t bytes) -> void* {
        void* p = (void*)w;
        w += (bytes + 255) & ~(size_t)255;
        return p;
    };
    unsigned short* bufHb = (unsigned short*)alloc((size_t)N * 256 * 2);
    float* bufX = (float*)alloc((size_t)Mpad * 256 * 4);      // f32 h2 (layer-2 output)
    unsigned short* X2h = (unsigned short*)bufX;              // alias: bf16 X2 plane, dead before bufX written
    float* asrc   = (float*)alloc((size_t)N * 4);
    float* adst   = (float*)alloc((size_t)N * 4);
    float* gate   = (float*)alloc((size_t)N * 4);
    int*   counts = (int*)alloc((size_t)N * 4);
    int*   rowptr = (int*)alloc((size_t)(N + 1) * 4);
    int*   cursor = (int*)alloc((size_t)N * 4);
    int*   colbuf = (int*)alloc((size_t)E * 4);
    int*   psum   = (int*)alloc(256 * 4);
    float* pmax   = (float*)alloc(256 * 4);
    float* gmaxv  = (float*)alloc(4 * 4);
    float* scal   = (float*)alloc(8 * 4);
    float* gout   = (float*)alloc(256 * 4);
    unsigned short* BT1 = (unsigned short*)alloc((size_t)256 * 768 * 2);
    unsigned short* BT2 = (unsigned short*)alloc((size_t)256 * 256 * 2);

    const int eb  = (E + 255) / 256;
    const int nb8 = (N + 7) / 8;
    const int nb  = (N + 255) / 256;
    const dim3 gg(Mpad / 128, 2);

    // weight transpose + rne-bf16 (single plane)
    k_convB<<<768, 256, 0, stream>>>(W1, BT1, 768);
    k_convB<<<256, 256, 0, stream>>>(W2, BT2, 256);

    // CSR by dst
    (void)hipMemsetAsync(counts, 0, (size_t)N * 4, stream);
    k_degree<<<eb, 256, 0, stream>>>(dstA, counts, E);
    k_part<<<nb, 256, 0, stream>>>(counts, psum, N);
    k_scan_part<<<1, 256, 0, stream>>>(psum, nb, rowptr + N);
    k_rowptr<<<nb, 256, 0, stream>>>(counts, psum, rowptr, cursor, N);
    k_scatter<<<eb, 256, 0, stream>>>(srcA, dstA, cursor, colbuf, E);

    // layer 1
    (void)hipMemsetAsync(asrc, 0, (size_t)N * 4, stream);
    (void)hipMemsetAsync(adst, 0, (size_t)N * 4, stream);
    k_gemm_f32A<<<gg, 512, 0, stream>>>(x, BT1, bufHb, asrc, adst, as1, ad1, N, 768);
    k_pmax<<<64, 256, 0, stream>>>(asrc, N, pmax);
    k_fold<<<1, 64, 0, stream>>>(pmax, gmaxv);
    k_edge<<<nb8, 256, 0, stream>>>(bufHb, asrc, adst, gmaxv, rowptr, colbuf, b1,
                                    nullptr, X2h, nullptr, nullptr, nullptr, N);

    // layer 2
    (void)hipMemsetAsync(asrc, 0, (size_t)N * 4, stream);
    (void)hipMemsetAsync(adst, 0, (size_t)N * 4, stream);
    k_gemm_bf16A<<<gg, 512, 0, stream>>>(X2h, BT2, bufHb, asrc, adst, as2, ad2, N, 256);
    k_pmax<<<64, 256, 0, stream>>>(asrc, N, pmax);
    k_fold<<<1, 64, 0, stream>>>(pmax, gmaxv);
    k_edge<<<nb8, 256, 0, stream>>>(bufHb, asrc, adst, gmaxv, rowptr, colbuf, b2,
                                    bufX, nullptr, gw, gb, gate, N);

    // global attention
    k_pmax<<<64, 256, 0, stream>>>(gate, N, pmax);
    k_gmid<<<1, 256, 0, stream>>>(pmax, 64, scal, gout);
    k_gout<<<256, 256, 0, stream>>>(bufX, gate, scal, gout, N);
    k_final<<<1, 256, 0, stream>>>(gout, scal, out);
}